// Round 1
// 283.569 us; speedup vs baseline: 1.0582x; 1.0582x over previous
//
#include <hip/hip_runtime.h>
#include <hip/hip_bf16.h>

#define D 128
#define HEADS 4
#define NEG_SLOPE 0.2f
#define QSCALE 0.0625f
#define QUNSCALE 16.0f

typedef __attribute__((ext_vector_type(8))) short short8;
typedef __attribute__((ext_vector_type(4))) float f32x4;
typedef __attribute__((ext_vector_type(2))) _Float16 h2;

__device__ __forceinline__ float lrelu(float v) {
    return fmaxf(v, NEG_SLOPE * v);   // valid since NEG_SLOPE < 1
}

__device__ __forceinline__ short f2bf(float v) {
    __hip_bfloat16 b = __float2bfloat16(v);
    short s;
    __builtin_memcpy(&s, &b, 2);
    return s;
}

__device__ __forceinline__ unsigned short f2h(float v) {
    _Float16 h = (_Float16)v;
    unsigned short s;
    __builtin_memcpy(&s, &h, 2);
    return s;
}

// ------- W prep: combined [W | skip_W] -> bf16 transposed wsT[256][128] -----
// Also initializes the fixed-stride bucket cursors for binA.
#define BCAP 4608
__global__ __launch_bounds__(256)
void wprep_kernel(const float* __restrict__ W, const float* __restrict__ S,
                  short* __restrict__ wsT, int* __restrict__ woffA, int nb) {
    int idx = blockIdx.x * 256 + threadIdx.x;   // 32768
    int nn = idx >> 7, k = idx & 127;
    float v = (nn < 128) ? W[k * D + nn] : S[k * D + (nn - 128)];
    wsT[idx] = f2bf(v);
    if (idx < nb) woffA[idx] = idx * BCAP;
}

// ------- MFMA combined GEMM + fused attention projections -------------------
// Block: 64 rows x 256 combined cols, 8 waves of 32x64. H-half waves (wc<2)
// also reduce a_s/a_d from their fp32 acc fragments (head = col>>5).
// hb/baseb are stored as FP16 (packed math in gather).
#define LDSPAD 136
__global__ __launch_bounds__(512, 4)
void gemm_mfma_kernel(const float* __restrict__ x, const short* __restrict__ wsT,
                      const float* __restrict__ skip_b, const float* __restrict__ gat_bias,
                      const float* __restrict__ att_src, const float* __restrict__ att_dst,
                      unsigned short* __restrict__ hb, unsigned short* __restrict__ baseb,
                      float* __restrict__ a_s, float* __restrict__ a_d, int n) {
    __shared__ short xs[64][LDSPAD];
    const int t = threadIdx.x;
    const int row0 = blockIdx.x * 64;
    #pragma unroll
    for (int i = 0; i < 4; ++i) {
        int f = t + 512 * i;                 // 0..2047
        int row = f >> 5, c4 = (f & 31) * 4;
        float4 v = make_float4(0.f, 0.f, 0.f, 0.f);
        if (row0 + row < n) v = *(const float4*)&x[(size_t)(row0 + row) * D + c4];
        short4 s4;
        s4.x = f2bf(v.x); s4.y = f2bf(v.y); s4.z = f2bf(v.z); s4.w = f2bf(v.w);
        *(short4*)&xs[row][c4] = s4;
    }
    __syncthreads();
    const int wv = t >> 6, lane = t & 63;
    const int lo = lane & 15, hi = lane >> 4;
    const int wr = wv >> 2;
    const int wc = wv & 3;
    f32x4 acc[2][4] = {};
    #pragma unroll
    for (int k0 = 0; k0 < 128; k0 += 32) {
        const int kk = k0 + hi * 8;
        short8 a0 = *(const short8*)&xs[wr * 32 + lo][kk];
        short8 a1 = *(const short8*)&xs[wr * 32 + 16 + lo][kk];
        #pragma unroll
        for (int nt = 0; nt < 4; ++nt) {
            short8 b = *(const short8*)&wsT[(wc * 64 + nt * 16 + lo) * D + kk];
            acc[0][nt] = __builtin_amdgcn_mfma_f32_16x16x32_bf16(a0, b, acc[0][nt], 0, 0, 0);
            acc[1][nt] = __builtin_amdgcn_mfma_f32_16x16x32_bf16(a1, b, acc[1][nt], 0, 0, 0);
        }
    }
    // fused a_s/a_d for the H half (cols 0..127): head = col>>5
    if (wc < 2) {
        float as_[4], ad_[4];
        #pragma unroll
        for (int nt = 0; nt < 4; ++nt) {
            const int c = wc * 64 + nt * 16 + lo;
            as_[nt] = att_src[c];
            ad_[nt] = att_dst[c];
        }
        #pragma unroll
        for (int mt = 0; mt < 2; ++mt) {
            #pragma unroll
            for (int reg = 0; reg < 4; ++reg) {
                float ps0 = acc[mt][0][reg] * as_[0] + acc[mt][1][reg] * as_[1];
                float ps1 = acc[mt][2][reg] * as_[2] + acc[mt][3][reg] * as_[3];
                float pd0 = acc[mt][0][reg] * ad_[0] + acc[mt][1][reg] * ad_[1];
                float pd1 = acc[mt][2][reg] * ad_[2] + acc[mt][3][reg] * ad_[3];
                #pragma unroll
                for (int off = 1; off < 16; off <<= 1) {
                    ps0 += __shfl_xor(ps0, off, 64);
                    ps1 += __shfl_xor(ps1, off, 64);
                    pd0 += __shfl_xor(pd0, off, 64);
                    pd1 += __shfl_xor(pd1, off, 64);
                }
                if (lo == 0) {
                    const int r = row0 + wr * 32 + mt * 16 + hi * 4 + reg;
                    if (r < n) {
                        a_s[r * HEADS + wc * 2 + 0] = ps0;
                        a_s[r * HEADS + wc * 2 + 1] = ps1;
                        a_d[r * HEADS + wc * 2 + 0] = pd0;
                        a_d[r * HEADS + wc * 2 + 1] = pd1;
                    }
                }
            }
        }
    }
    // epilogue: C/D layout col=lane&15, row=(lane>>4)*4+reg  (stores FP16)
    #pragma unroll
    for (int nt = 0; nt < 4; ++nt) {
        const int cc = wc * 64 + nt * 16 + lo;
        const bool isH = cc < 128;
        const float bb = isH ? 0.f : (skip_b[cc - 128] + gat_bias[cc - 128]);
        unsigned short* dst = isH ? hb : baseb;
        const int c = isH ? cc : cc - 128;
        #pragma unroll
        for (int mt = 0; mt < 2; ++mt) {
            const int rbase = row0 + wr * 32 + mt * 16 + hi * 4;
            #pragma unroll
            for (int reg = 0; reg < 4; ++reg) {
                const int r = rbase + reg;
                if (r < n) dst[(size_t)r * D + c] = f2h(acc[mt][nt][reg] + bb);
            }
        }
    }
}

// ================= One-pass bucketed scatter (fixed-stride buckets) =========
// pairs packed 32-bit: (src << 8) | (dst & 255)
#define BEPT 16
#define BCHUNK (256 * BEPT)

__global__ __launch_bounds__(256)
void binA_kernel(const int* __restrict__ ei, int* __restrict__ woffA,
                 unsigned int* __restrict__ pairs, int E_, int nb) {
    __shared__ int hist[512];
    __shared__ int gbase[512];
    const int t = threadIdx.x;
    for (int q = t; q < 512; q += 256) hist[q] = 0;
    __syncthreads();
    int sv[BEPT], dv[BEPT], rk[BEPT];
    const int base = blockIdx.x * BCHUNK;
    #pragma unroll
    for (int i = 0; i < BEPT; ++i) {
        int e = base + i * 256 + t;
        if (e < E_) {
            sv[i] = ei[e];
            dv[i] = ei[E_ + e];
            rk[i] = atomicAdd(&hist[dv[i] >> 8], 1);
        } else {
            sv[i] = -1;
        }
    }
    __syncthreads();
    for (int q = t; q < nb; q += 256) {
        int v = hist[q];
        gbase[q] = v ? atomicAdd(&woffA[q], v) : 0;
    }
    __syncthreads();
    #pragma unroll
    for (int i = 0; i < BEPT; ++i) {
        if (sv[i] >= 0) {
            int pos = gbase[dv[i] >> 8] + rk[i];
            pairs[pos] = ((unsigned int)sv[i] << 8) | (unsigned int)(dv[i] & 255);
        }
    }
}

// ---- pass B: one block per bucket; single pass, edges cached in registers --
#define KCAP 24
__global__ __launch_bounds__(256)
void binB_kernel(const unsigned int* __restrict__ pairs, const int* __restrict__ wcur,
                 int* __restrict__ cnt, int* __restrict__ offs,
                 int* __restrict__ ssrc, int n) {
    __shared__ int nhist[256];
    __shared__ int sc[256];
    __shared__ int nbase[256];
    const int b = blockIdx.x;
    const int t = threadIdx.x;
    const int node0 = b << 8;
    const int sbeg = b * BCAP, send = wcur[b];
    nhist[t] = 0;
    __syncthreads();
    unsigned int pk[KCAP];
    int rk[KCAP];
    int nl = 0;
    for (int e = sbeg + t; e < send; e += 256) {
        unsigned int p = pairs[e];
        int r = atomicAdd(&nhist[p & 255], 1);
        if (nl < KCAP) { pk[nl] = p; rk[nl] = r; }
        ++nl;
    }
    __syncthreads();
    int v = nhist[t];
    sc[t] = v;
    __syncthreads();
    for (int off = 1; off < 256; off <<= 1) {
        int x = (t >= off) ? sc[t - off] : 0;
        __syncthreads();
        sc[t] += x;
        __syncthreads();
    }
    int ex = sc[t] - v;
    nbase[t] = sbeg + ex;
    if (node0 + t < n) {
        cnt[node0 + t] = v;
        offs[node0 + t] = sbeg + ex;
    }
    __syncthreads();
    const int m = nl < KCAP ? nl : KCAP;
    for (int i = 0; i < m; ++i) {
        int pos = nbase[pk[i] & 255] + rk[i];
        ssrc[pos] = (int)(pk[i] >> 8);
    }
}

// ---------------- Gather: wave/node; FP16 packed accumulation ---------------
__global__ __launch_bounds__(256)
void gather_kernel(const int* __restrict__ offs, const int* __restrict__ cnt,
                   const int* __restrict__ ssrc, const float* __restrict__ a_s,
                   const float* __restrict__ a_d, const uint2* __restrict__ hb4,
                   const uint2* __restrict__ baseb4,
                   const float* __restrict__ ln_g, const float* __restrict__ ln_b,
                   float* __restrict__ out, int n) {
    const int lane = threadIdx.x & 63;
    const int i = blockIdx.x * 4 + (threadIdx.x >> 6);
    if (i >= n) return;
    const int e4 = lane >> 2, h4 = lane & 3;
    const int l31 = lane & 31;
    const int myhead = l31 >> 3;
    const int esel = (lane < 32) ? 0 : 1;
    // prefetch tail operands off the critical path
    const uint2 bv = baseb4[(size_t)i * 32 + l31];
    const float4 g4 = ((const float4*)ln_g)[l31];
    const float4 lb4 = ((const float4*)ln_b)[l31];
    const float as_h4 = a_s[i * HEADS + h4];
    const float ad_h4 = a_d[i * HEADS + h4];
    const float qself = __expf(lrelu(as_h4 + ad_h4));
    float zacc = (e4 == 0) ? qself : 0.f;
    h2 acc01, acc23;
    {
        uint2 u = hb4[(size_t)i * 32 + l31];
        float qs = __shfl(qself, myhead, 64) * QSCALE;
        float w = (lane < 32) ? qs : 0.f;
        const _Float16 wh = (_Float16)w;
        const h2 w2 = {wh, wh};
        acc01 = __builtin_bit_cast(h2, u.x) * w2;
        acc23 = __builtin_bit_cast(h2, u.y) * w2;
    }
    const int o = offs[i];
    const int c = cnt[i];
    for (int k0 = 0; k0 < c; k0 += 16) {
        const int rem = c - k0;
        int srow = 0;
        float q = 0.f;
        if (e4 < rem) {
            const int sidx = ssrc[o + k0 + e4];
            srow = sidx << 5;
            q = __expf(lrelu(a_s[sidx * HEADS + h4] + ad_h4));
        }
        zacc += q;
        const _Float16 qh = (_Float16)(q * QSCALE);
        const h2 qv = {qh, qh};
        const int qpk = __builtin_bit_cast(int, qv);
        const int m = rem < 16 ? rem : 16;
        int ee = 0;
        for (; ee + 8 <= m; ee += 8) {
            const int sl0 = (ee + 0 + esel) * 4;
            const int sl1 = (ee + 2 + esel) * 4;
            const int sl2 = (ee + 4 + esel) * 4;
            const int sl3 = (ee + 6 + esel) * 4;
            const int rA = __shfl(srow, sl0, 64) + l31;
            const int rB = __shfl(srow, sl1, 64) + l31;
            const int rC = __shfl(srow, sl2, 64) + l31;
            const int rD = __shfl(srow, sl3, 64) + l31;
            const h2 qA = __builtin_bit_cast(h2, __shfl(qpk, sl0 + myhead, 64));
            const h2 qB = __builtin_bit_cast(h2, __shfl(qpk, sl1 + myhead, 64));
            const h2 qC = __builtin_bit_cast(h2, __shfl(qpk, sl2 + myhead, 64));
            const h2 qD = __builtin_bit_cast(h2, __shfl(qpk, sl3 + myhead, 64));
            const uint2 uA = hb4[(size_t)(unsigned)rA];
            const uint2 uB = hb4[(size_t)(unsigned)rB];
            const uint2 uC = hb4[(size_t)(unsigned)rC];
            const uint2 uD = hb4[(size_t)(unsigned)rD];
            acc01 += __builtin_bit_cast(h2, uA.x) * qA;
            acc23 += __builtin_bit_cast(h2, uA.y) * qA;
            acc01 += __builtin_bit_cast(h2, uB.x) * qB;
            acc23 += __builtin_bit_cast(h2, uB.y) * qB;
            acc01 += __builtin_bit_cast(h2, uC.x) * qC;
            acc23 += __builtin_bit_cast(h2, uC.y) * qC;
            acc01 += __builtin_bit_cast(h2, uD.x) * qD;
            acc23 += __builtin_bit_cast(h2, uD.y) * qD;
        }
        for (; ee < m; ee += 2) {
            const int sl = (ee + esel) * 4;
            const int rA = __shfl(srow, sl, 64) + l31;
            const h2 qA = __builtin_bit_cast(h2, __shfl(qpk, sl + myhead, 64));
            const uint2 uA = hb4[(size_t)(unsigned)rA];
            acc01 += __builtin_bit_cast(h2, uA.x) * qA;
            acc23 += __builtin_bit_cast(h2, uA.y) * qA;
        }
    }
    float acc0 = (float)acc01.x;
    float acc1 = (float)acc01.y;
    float acc2 = (float)acc23.x;
    float acc3 = (float)acc23.y;
    acc0 += __shfl_xor(acc0, 32, 64);
    acc1 += __shfl_xor(acc1, 32, 64);
    acc2 += __shfl_xor(acc2, 32, 64);
    acc3 += __shfl_xor(acc3, 32, 64);
    #pragma unroll
    for (int off = 4; off < 64; off <<= 1) zacc += __shfl_xor(zacc, off, 64);
    const float zz = __shfl(zacc, myhead, 64);
    const float rz = QUNSCALE / (zz + 1e-16f);
    const h2 b01 = __builtin_bit_cast(h2, bv.x);
    const h2 b23 = __builtin_bit_cast(h2, bv.y);
    float v0 = acc0 * rz + (float)b01.x;
    float v1 = acc1 * rz + (float)b01.y;
    float v2 = acc2 * rz + (float)b23.x;
    float v3 = acc3 * rz + (float)b23.y;
    float s1 = v0 + v1 + v2 + v3;
    float s2 = v0 * v0 + v1 * v1 + v2 * v2 + v3 * v3;
    #pragma unroll
    for (int off = 1; off < 32; off <<= 1) {
        s1 += __shfl_xor(s1, off, 64);
        s2 += __shfl_xor(s2, off, 64);
    }
    const float mu = s1 * (1.f / 128.f);
    const float var = s2 * (1.f / 128.f) - mu * mu;
    const float r = rsqrtf(var + 1e-5f);
    if (lane < 32) {
        float4 o4;
        o4.x = (v0 - mu) * r * g4.x + lb4.x;
        o4.y = (v1 - mu) * r * g4.y + lb4.y;
        o4.z = (v2 - mu) * r * g4.z + lb4.z;
        o4.w = (v3 - mu) * r * g4.w + lb4.w;
        ((float4*)out)[(size_t)i * 32 + l31] = o4;
    }
}

extern "C" void kernel_launch(void* const* d_in, const int* in_sizes, int n_in,
                              void* d_out, int out_size, void* d_ws, size_t ws_size,
                              hipStream_t stream) {
    const float* x        = (const float*)d_in[0];
    const int*   ei       = (const int*)d_in[1];
    const float* W        = (const float*)d_in[2];
    const float* att_src  = (const float*)d_in[3];
    const float* att_dst  = (const float*)d_in[4];
    const float* gat_bias = (const float*)d_in[5];
    const float* skip_W   = (const float*)d_in[6];
    const float* skip_b   = (const float*)d_in[7];
    const float* ln_g     = (const float*)d_in[8];
    const float* ln_b     = (const float*)d_in[9];
    float* out = (float*)d_out;

    const int n  = in_sizes[0] / D;   // 100000
    const int E_ = in_sizes[1] / 2;   // 1600000
    const int nb = (n + 255) >> 8;

    char* p = (char*)d_ws;
    auto carve = [&p](size_t bytes) {
        char* r = p;
        p += (bytes + 255) & ~(size_t)255;
        return r;
    };
    short* wsT            = (short*)carve(32768 * sizeof(short));
    unsigned short* hb    = (unsigned short*)carve((size_t)n * D * 2);
    unsigned short* baseb = (unsigned short*)carve((size_t)n * D * 2);
    float* a_s            = (float*)carve((size_t)n * HEADS * 4);
    float* a_d            = (float*)carve((size_t)n * HEADS * 4);
    int*   cnt            = (int*)carve((size_t)n * 4);
    int*   offs           = (int*)carve((size_t)n * 4);
    int*   woffA          = (int*)carve(512 * 4);
    int*   ssrc           = (int*)carve((size_t)nb * BCAP * 4);
    unsigned int* pairs   = (unsigned int*)carve((size_t)nb * BCAP * 4);

    wprep_kernel<<<128, 256, 0, stream>>>(W, skip_W, wsT, woffA, nb);
    gemm_mfma_kernel<<<(n + 63) / 64, 512, 0, stream>>>(x, wsT, skip_b, gat_bias,
                                                        att_src, att_dst,
                                                        hb, baseb, a_s, a_d, n);
    const int BA = (E_ + BCHUNK - 1) / BCHUNK;
    binA_kernel<<<BA, 256, 0, stream>>>(ei, woffA, pairs, E_, nb);
    binB_kernel<<<nb, 256, 0, stream>>>(pairs, woffA, cnt, offs, ssrc, n);
    gather_kernel<<<(n + 3) / 4, 256, 0, stream>>>(offs, cnt, ssrc, a_s, a_d,
                                                   (const uint2*)hb,
                                                   (const uint2*)baseb,
                                                   ln_g, ln_b, out, n);
}